// Round 4
// baseline (187.797 us; speedup 1.0000x reference)
//
#include <hip/hip_runtime.h>

#define BATCH 8
#define CCH   128
#define DQK   16
#define HW    4096   // N = H*W
#define LOG2E 1.44269504088896340736f

typedef __attribute__((ext_vector_type(8))) short bf16x8;   // 8 bf16 = 4 VGPRs
typedef __attribute__((ext_vector_type(4))) float f32x4;

// pack two f32 -> packed bf16 pair (lo, hi), single HW instruction
__device__ __forceinline__ unsigned cvt_pk_bf16(float lo, float hi) {
    unsigned r;
    asm("v_cvt_pk_bf16_f32 %0, %1, %2" : "=v"(r) : "v"(lo), "v"(hi));
    return r;
}

// async global->LDS, 16B per lane. LDS dest must be linear (base + lane*16)
// across the wave; global src is per-lane (CK-style casts).
__device__ __forceinline__ void glds16(const void* gsrc, const void* lds) {
    auto* g = (const __attribute__((address_space(1))) unsigned int*)(unsigned long long)(uintptr_t)gsrc;
    auto* s = (__attribute__((address_space(3))) unsigned int*)(unsigned int)(uintptr_t)lds;
    __builtin_amdgcn_global_load_lds(g, s, 16, 0, 0);
}

// ------------------------------------------------------------------
// Kernel A: q/k/v 1x1 conv projections via bf16 MFMA.
// grid = 512 blocks x 256 threads (4 waves). Block owns 64 pixels.
// A-frags (W rows) load DIRECTLY from global fp32 (L2-resident 80KB) +
// in-reg cvt -> no W LDS staging (round-3's 78us was this staging loop).
// Only x^T is LDS-staged (17KB). Wave w owns pixel-tile w (16 px);
// 10 o-tiles x 4 k-steps = 40 MFMA. Per-ot W array is wave-uniform
// (o = ot*16 + lm: ot=0 -> Wq, ot=1 -> Wk, ot>=2 -> Wv).
// q,k stored transposed [b][pixel][16] (q pre-scaled by LOG2E);
// v stored [b][c][pixel].
// ------------------------------------------------------------------
__global__ __launch_bounds__(256) void qkv_kernel(
    const float* __restrict__ x,
    const float* __restrict__ Wq, const float* __restrict__ bq,
    const float* __restrict__ Wk, const float* __restrict__ bk,
    const float* __restrict__ Wv, const float* __restrict__ bv,
    ushort* __restrict__ qT, ushort* __restrict__ kT, ushort* __restrict__ v)
{
    const int blk = blockIdx.x;
    const int b   = blk >> 6;
    const int p0  = (blk & 63) << 6;
    const int t   = threadIdx.x;
    const int l   = t & 63;
    const int w   = t >> 6;
    const int lm  = l & 15;
    const int lg  = l >> 4;

    // stride 136 ushorts = 272B (17x16B): rows 16B-aligned, b128-friendly
    __shared__ __align__(16) ushort xT_l[64 * 136];

    // ---- stage x^T tile: lane = pixel, c-octet oc = w + 4*it ----
#pragma unroll
    for (int it = 0; it < 4; it++) {
        const int oc = w + 4 * it;          // c-octet 0..15
        float xr[8];
#pragma unroll
        for (int r = 0; r < 8; r++)
            xr[r] = x[((size_t)(b * CCH + oc * 8 + r)) * HW + p0 + l];
        unsigned u[4];
#pragma unroll
        for (int r = 0; r < 4; r++) u[r] = cvt_pk_bf16(xr[2 * r], xr[2 * r + 1]);
        *(bf16x8*)&xT_l[l * 136 + oc * 8] = *(bf16x8*)u;
    }
    __syncthreads();

    // ---- B-frags: 4 LDS reads, kept in regs for all 10 o-tiles ----
    bf16x8 bfrag[4];
#pragma unroll
    for (int ks = 0; ks < 4; ks++)
        bfrag[ks] = *(const bf16x8*)&xT_l[(w * 16 + lm) * 136 + ks * 32 + lg * 8];

    f32x4 acc[10];
#pragma unroll
    for (int ot = 0; ot < 10; ot++)
#pragma unroll
        for (int r = 0; r < 4; r++) acc[ot][r] = 0.f;

    // ---- MFMA: A-frag = W[o = ot*16+lm][k = ks*32 + lg*8 ..+8] from global ----
#pragma unroll
    for (int ot = 0; ot < 10; ot++) {
        const float* Wrow;
        if (ot == 0)      Wrow = Wq + lm * CCH;
        else if (ot == 1) Wrow = Wk + lm * CCH;
        else              Wrow = Wv + (ot * 16 - 32 + lm) * CCH;
        const float scale = (ot == 0) ? LOG2E : 1.f;
#pragma unroll
        for (int ks = 0; ks < 4; ks++) {
            const float4 wa = *(const float4*)(Wrow + ks * 32 + lg * 8);
            const float4 wb = *(const float4*)(Wrow + ks * 32 + lg * 8 + 4);
            unsigned u[4];
            u[0] = cvt_pk_bf16(wa.x * scale, wa.y * scale);
            u[1] = cvt_pk_bf16(wa.z * scale, wa.w * scale);
            u[2] = cvt_pk_bf16(wb.x * scale, wb.y * scale);
            u[3] = cvt_pk_bf16(wb.z * scale, wb.w * scale);
            const bf16x8 afrag = *(bf16x8*)u;
            acc[ot] = __builtin_amdgcn_mfma_f32_16x16x32_bf16(afrag, bfrag[ks], acc[ot], 0, 0, 0);
        }
    }

    // ---- epilogue: D col=lm -> pixel, row=4lg+r -> o; bias direct from global ----
    const int px = p0 + w * 16 + lm;
#pragma unroll
    for (int ot = 0; ot < 10; ot++) {
        const int ob = ot * 16 + 4 * lg;
        float4 bb;
        if (ot == 0) {
            bb = *(const float4*)(bq + 4 * lg);
            bb.x *= LOG2E; bb.y *= LOG2E; bb.z *= LOG2E; bb.w *= LOG2E;
        } else if (ot == 1) {
            bb = *(const float4*)(bk + 4 * lg);
        } else {
            bb = *(const float4*)(bv + (ot - 2) * 16 + 4 * lg);
        }
        const float r0 = acc[ot][0] + bb.x, r1 = acc[ot][1] + bb.y;
        const float r2 = acc[ot][2] + bb.z, r3 = acc[ot][3] + bb.w;
        const unsigned w0 = cvt_pk_bf16(r0, r1), w1 = cvt_pk_bf16(r2, r3);
        if (ot == 0) {
            uint2 pk; pk.x = w0; pk.y = w1;
            *(uint2*)&qT[((size_t)(b * HW + px)) * DQK + ob] = pk;
        } else if (ot == 1) {
            uint2 pk; pk.x = w0; pk.y = w1;
            *(uint2*)&kT[((size_t)(b * HW + px)) * DQK + (ob - 16)] = pk;
        } else {
            const int c = ob - 32;
            v[((size_t)(b * CCH + c + 0)) * HW + px] = (ushort)(w0 & 0xffff);
            v[((size_t)(b * CCH + c + 1)) * HW + px] = (ushort)(w0 >> 16);
            v[((size_t)(b * CCH + c + 2)) * HW + px] = (ushort)(w1 & 0xffff);
            v[((size_t)(b * CCH + c + 3)) * HW + px] = (ushort)(w1 >> 16);
        }
    }
}

// ------------------------------------------------------------------
// Kernel B: flash attention, bf16 MFMA 16x16x32, KVBLK = 128.
// grid = 512 x 256 (4 waves). Block owns 64 query rows; wave w owns
// i-range [16w,16w+16). Softmax in exp2 domain (log2e folded into q).
// Staging via global_load_lds w=16: kT linear; v_l linear LDS dest with
// PRE-SWIZZLED global source (granule g ^= (c&15), involution), so PV
// reads use the same swizzle (2-way free). kT_l is [j][16] with no
// K=32 zero-padding: only qf (B operand) needs zeros for k>=16; kf
// lanes lg>=2 are exec-masked off. T13 defer-rescale; T5 setprio on PV.
// ------------------------------------------------------------------
__global__ __launch_bounds__(256) void attn_kernel(
    const ushort* __restrict__ qT, const ushort* __restrict__ kTg,
    const ushort* __restrict__ vg, const float* __restrict__ x,
    const float* __restrict__ gamma, float* __restrict__ out)
{
    // XCD swizzle: 512 = 8 XCDs x 64; each XCD gets one batch (K/V L2-resident)
    const int blk = ((blockIdx.x & 7) << 6) | (blockIdx.x >> 3);
    const int b   = blk >> 6;
    const int i0  = (blk & 63) << 6;
    const int t   = threadIdx.x;
    const int l   = t & 63;
    const int w   = t >> 6;
    const int lm  = l & 15;   // B-operand lane idx -> D col
    const int lg  = l >> 4;

    __shared__ __align__(16) ushort kT_l[128 * 16];    // 4KB  [j][16] linear
    __shared__ __align__(16) ushort v_l [128 * 128];   // 32KB [c][128j] swizzled granules
    __shared__ __align__(16) ushort P_l [64 * 128];    // 16KB [i][128j] swizzled granules

    // ---- per-lane glds addresses (linear LDS dest; swizzled global src) ----
    const ushort* kT_src = kTg + ((size_t)b * HW) * DQK + t * 8;
    ushort*       kT_dst = &kT_l[t * 8];
    const ushort* v_src[8];
    ushort*       v_dst[8];
#pragma unroll
    for (int it = 0; it < 8; it++) {
        const int idx = t + 256 * it;
        const int c   = idx >> 4;
        const int gs  = (idx & 15) ^ (c & 15);      // involutive granule swizzle
        v_src[it] = vg + ((size_t)(b * CCH + c)) * HW + gs * 8;
        v_dst[it] = &v_l[idx * 8];
    }

    // Q B-frag (log2e pre-folded): lane needs q[i = i0+16w+lm][d = lg*8..]; lg>=2 zero
    bf16x8 qf;
#pragma unroll
    for (int z = 0; z < 8; z++) qf[z] = 0;
    if (lg < 2)
        qf = *(const bf16x8*)(qT + ((size_t)(b * HW + i0 + 16 * w + lm)) * DQK + lg * 8);

    f32x4 zero4;
#pragma unroll
    for (int z = 0; z < 4; z++) zero4[z] = 0.f;

    f32x4 acc[8];
#pragma unroll
    for (int ct = 0; ct < 8; ct++) acc[ct] = zero4;

    float m_i = -1e30f, l_i = 0.f;

    for (int j0 = 0; j0 < HW; j0 += 128) {
        __syncthreads();   // previous tile fully consumed

        // ---- async stage: kT (1 glds) + v (8 glds), drained by next barrier ----
        glds16(kT_src + (size_t)j0 * DQK, kT_dst);
#pragma unroll
        for (int it = 0; it < 8; it++)
            glds16(v_src[it] + j0, v_dst[it]);
        __syncthreads();   // emits s_waitcnt vmcnt(0) before s_barrier

        // ---- S^T = mfma(K,Q): s[jt][r] = S[i][j = j0 + jt*16 + lg*4 + r] (exp2 dom) ----
        f32x4 s[8];
#pragma unroll
        for (int jt = 0; jt < 8; jt++) {
            bf16x8 kf = {};
            if (lg < 2)    // exec-masked half-wave read; k>=16 killed by qf zeros
                kf = *(const bf16x8*)&kT_l[(jt * 16 + lm) * 16 + lg * 8];
            s[jt] = __builtin_amdgcn_mfma_f32_16x16x32_bf16(kf, qf, zero4, 0, 0, 0);
        }

        // ---- online softmax, one i per lane ----
        float mx = s[0][0];
#pragma unroll
        for (int jt = 0; jt < 8; jt++)
#pragma unroll
            for (int r = 0; r < 4; r++) mx = fmaxf(mx, s[jt][r]);
        mx = fmaxf(mx, __shfl_xor(mx, 16));
        mx = fmaxf(mx, __shfl_xor(mx, 32));

        float m_new, alpha;
        if (__all(mx - m_i <= 8.f)) {           // T13 defer-rescale
            m_new = m_i; alpha = 1.f;
        } else {
            m_new = fmaxf(m_i, mx);
            alpha = exp2f(m_i - m_new);
#pragma unroll
            for (int ct = 0; ct < 8; ct++) acc[ct] *= alpha;
        }

        float sum = 0.f;
        const int prow = (16 * w + lm) * 128;
#pragma unroll
        for (int jt = 0; jt < 8; jt++) {
            const float p0f = exp2f(s[jt][0] - m_new);
            const float p1f = exp2f(s[jt][1] - m_new);
            const float p2f = exp2f(s[jt][2] - m_new);
            const float p3f = exp2f(s[jt][3] - m_new);
            sum += (p0f + p1f) + (p2f + p3f);
            uint2 pk;
            pk.x = cvt_pk_bf16(p0f, p1f);
            pk.y = cvt_pk_bf16(p2f, p3f);
            const int g = (2 * jt + (lg >> 1)) ^ lm;   // swizzled granule
            *(uint2*)&P_l[prow + g * 8 + (lg & 1) * 4] = pk;
        }
        sum += __shfl_xor(sum, 16);
        sum += __shfl_xor(sum, 32);
        l_i = l_i * alpha + sum;
        m_i = m_new;

        // ---- PV: acc[ct] += v-tile(ct) . P^T (same-wave LDS, lgkmcnt-ordered) ----
        __builtin_amdgcn_s_setprio(1);
#pragma unroll
        for (int ks = 0; ks < 4; ks++) {
            const int g = (4 * ks + lg) ^ lm;          // same swizzle both reads
            const bf16x8 pf = *(const bf16x8*)&P_l[prow + g * 8];
#pragma unroll
            for (int ct = 0; ct < 8; ct++) {
                const bf16x8 vf = *(const bf16x8*)&v_l[(ct * 16 + lm) * 128 + g * 8];
                acc[ct] = __builtin_amdgcn_mfma_f32_16x16x32_bf16(vf, pf, acc[ct], 0, 0, 0);
            }
        }
        __builtin_amdgcn_s_setprio(0);
    }

    // ---- epilogue: out = gamma * (acc / l) + x ----
    const float linv = 1.f / l_i;
    const float gm = gamma[0];
    const int i = 16 * w + lm;
#pragma unroll
    for (int ct = 0; ct < 8; ct++) {
#pragma unroll
        for (int r = 0; r < 4; r++) {
            const int c = ct * 16 + lg * 4 + r;
            const size_t off = ((size_t)(b * CCH + c)) * HW + i0 + i;
            out[off] = gm * (acc[ct][r] * linv) + x[off];
        }
    }
}

extern "C" void kernel_launch(void* const* d_in, const int* in_sizes, int n_in,
                              void* d_out, int out_size, void* d_ws, size_t ws_size,
                              hipStream_t stream)
{
    const float* x     = (const float*)d_in[0];
    const float* Wq    = (const float*)d_in[1];
    const float* bq    = (const float*)d_in[2];
    const float* Wk    = (const float*)d_in[3];
    const float* bk    = (const float*)d_in[4];
    const float* Wv    = (const float*)d_in[5];
    const float* bv    = (const float*)d_in[6];
    const float* gamma = (const float*)d_in[7];
    float* out = (float*)d_out;

    ushort* qT = (ushort*)d_ws;                          // [8][4096][16] bf16 (x log2e)
    ushort* kT = qT + (size_t)BATCH * HW * DQK;          // [8][4096][16] bf16
    ushort* v  = kT + (size_t)BATCH * HW * DQK;          // [8][128][4096] bf16

    qkv_kernel<<<dim3(BATCH * (HW / 64)), dim3(256), 0, stream>>>(
        x, Wq, bq, Wk, bk, Wv, bv, qT, kT, v);
    attn_kernel<<<dim3(BATCH * (HW / 64)), dim3(256), 0, stream>>>(
        qT, kT, v, x, gamma, out);
}

// Round 5
// 173.470 us; speedup vs baseline: 1.0826x; 1.0826x over previous
//
#include <hip/hip_runtime.h>

#define BATCH 8
#define CCH   128
#define DQK   16
#define HW    4096   // N = H*W
#define LOG2E 1.44269504088896340736f
#define KTS   24     // kT padded row stride in ushorts (48B = 3 granules, 2-way-free b128)
#define WTS   136    // W padded row stride in ushorts (272B = 17 granules, 2-way-free b128)
#define WGRAN 2816   // W staged granules (2720 real, padded to 11*256 for uniform glds)

typedef __attribute__((ext_vector_type(8))) short bf16x8;   // 8 bf16 = 4 VGPRs
typedef __attribute__((ext_vector_type(4))) float f32x4;

// pack two f32 -> packed bf16 pair (lo, hi), single HW instruction
__device__ __forceinline__ unsigned cvt_pk_bf16(float lo, float hi) {
    unsigned r;
    asm("v_cvt_pk_bf16_f32 %0, %1, %2" : "=v"(r) : "v"(lo), "v"(hi));
    return r;
}

// async global->LDS, 16B per lane. LDS dest must be linear (base + lane*16)
// across the wave; global src is per-lane.
__device__ __forceinline__ void glds16(const void* gsrc, const void* lds) {
    auto* g = (const __attribute__((address_space(1))) unsigned int*)(unsigned long long)(uintptr_t)gsrc;
    auto* s = (__attribute__((address_space(3))) unsigned int*)(unsigned int)(uintptr_t)lds;
    __builtin_amdgcn_global_load_lds(g, s, 16, 0, 0);
}

// ------------------------------------------------------------------
// Kernel P: one-time W -> bf16 pre-convert into padded [160][WTS]
// layout (LOG2E folded into Wq rows). Pad cols zeroed. Runs every
// launch (no static state). 10880 uint writes over 43 blocks.
// ------------------------------------------------------------------
__global__ __launch_bounds__(256) void prep_kernel(
    const float* __restrict__ Wq, const float* __restrict__ Wk,
    const float* __restrict__ Wv, ushort* __restrict__ Wpad)
{
    const int idx = blockIdx.x * 256 + threadIdx.x;
    if (idx >= 160 * (WTS / 2)) return;
    const int row = idx / (WTS / 2);
    const int c0  = (idx % (WTS / 2)) * 2;
    unsigned val = 0;
    if (c0 < CCH) {
        const float* src;
        float sc = 1.f;
        if (row < 16)       { src = Wq + row * CCH;        sc = LOG2E; }
        else if (row < 32)  { src = Wk + (row - 16) * CCH; }
        else                { src = Wv + (row - 32) * CCH; }
        val = cvt_pk_bf16(src[c0] * sc, src[c0 + 1] * sc);
    }
    *(unsigned*)&Wpad[row * WTS + c0] = val;
}

// ------------------------------------------------------------------
// Kernel A: q/k/v 1x1 conv projections via bf16 MFMA.
// grid = 512 blocks x 256 threads (4 waves). Block owns 64 pixels.
// W staged via 11 fully-coalesced glds16/thread from pre-padded bf16
// global (no per-block cvt, no scattered loads). xT staged scalar-
// coalesced + cvt (R4 path, known-good). 10 o-tiles x 4 k = 40 MFMA.
// q stored [b][px][16] (xLOG2E); kT stored PADDED [b][px][KTS];
// v stored [b][c][px].
// ------------------------------------------------------------------
__global__ __launch_bounds__(256) void qkv_kernel(
    const float* __restrict__ x, const ushort* __restrict__ Wpad,
    const float* __restrict__ bq, const float* __restrict__ bk,
    const float* __restrict__ bv,
    ushort* __restrict__ qT, ushort* __restrict__ kT, ushort* __restrict__ v)
{
    const int blk = blockIdx.x;
    const int b   = blk >> 6;
    const int p0  = (blk & 63) << 6;
    const int t   = threadIdx.x;
    const int l   = t & 63;
    const int w   = t >> 6;
    const int lm  = l & 15;
    const int lg  = l >> 4;

    __shared__ __align__(16) ushort W_l[WGRAN * 8];    // 45056 B (incl. slack)
    __shared__ __align__(16) ushort xT_l[64 * WTS];    // 17408 B

    // ---- stage W via async glds: 11 granules per thread, coalesced ----
#pragma unroll
    for (int i = 0; i < 11; i++) {
        const int idx = t + 256 * i;
        glds16(Wpad + idx * 8, &W_l[idx * 8]);
    }

    // ---- stage x^T tile: lane = pixel, c-octet oc = w + 4*it ----
#pragma unroll
    for (int it = 0; it < 4; it++) {
        const int oc = w + 4 * it;          // c-octet 0..15
        float xr[8];
#pragma unroll
        for (int r = 0; r < 8; r++)
            xr[r] = x[((size_t)(b * CCH + oc * 8 + r)) * HW + p0 + l];
        unsigned u[4];
#pragma unroll
        for (int r = 0; r < 4; r++) u[r] = cvt_pk_bf16(xr[2 * r], xr[2 * r + 1]);
        *(bf16x8*)&xT_l[l * WTS + oc * 8] = *(bf16x8*)u;
    }
    __syncthreads();   // drains vmcnt (glds) + lgkmcnt (ds_write)

    // ---- B-frags: 4 LDS reads, kept in regs for all 10 o-tiles ----
    bf16x8 bfrag[4];
#pragma unroll
    for (int ks = 0; ks < 4; ks++)
        bfrag[ks] = *(const bf16x8*)&xT_l[(w * 16 + lm) * WTS + ks * 32 + lg * 8];

    f32x4 acc[10];
#pragma unroll
    for (int ot = 0; ot < 10; ot++)
#pragma unroll
        for (int r = 0; r < 4; r++) acc[ot][r] = 0.f;

#pragma unroll
    for (int ot = 0; ot < 10; ot++) {
#pragma unroll
        for (int ks = 0; ks < 4; ks++) {
            const bf16x8 afrag = *(const bf16x8*)&W_l[(ot * 16 + lm) * WTS + ks * 32 + lg * 8];
            acc[ot] = __builtin_amdgcn_mfma_f32_16x16x32_bf16(afrag, bfrag[ks], acc[ot], 0, 0, 0);
        }
    }

    // ---- epilogue: D col=lm -> pixel, row=4lg+r -> o; bias from global ----
    const int px = p0 + w * 16 + lm;
#pragma unroll
    for (int ot = 0; ot < 10; ot++) {
        const int ob = ot * 16 + 4 * lg;
        float4 bb;
        if (ot == 0) {
            bb = *(const float4*)(bq + 4 * lg);
            bb.x *= LOG2E; bb.y *= LOG2E; bb.z *= LOG2E; bb.w *= LOG2E;
        } else if (ot == 1) {
            bb = *(const float4*)(bk + 4 * lg);
        } else {
            bb = *(const float4*)(bv + (ot - 2) * 16 + 4 * lg);
        }
        const float r0 = acc[ot][0] + bb.x, r1 = acc[ot][1] + bb.y;
        const float r2 = acc[ot][2] + bb.z, r3 = acc[ot][3] + bb.w;
        const unsigned w0 = cvt_pk_bf16(r0, r1), w1 = cvt_pk_bf16(r2, r3);
        if (ot == 0) {
            uint2 pk; pk.x = w0; pk.y = w1;
            *(uint2*)&qT[((size_t)(b * HW + px)) * DQK + ob] = pk;
        } else if (ot == 1) {
            uint2 pk; pk.x = w0; pk.y = w1;
            *(uint2*)&kT[((size_t)(b * HW + px)) * KTS + (ob - 16)] = pk;
        } else {
            const int c = ob - 32;
            v[((size_t)(b * CCH + c + 0)) * HW + px] = (ushort)(w0 & 0xffff);
            v[((size_t)(b * CCH + c + 1)) * HW + px] = (ushort)(w0 >> 16);
            v[((size_t)(b * CCH + c + 2)) * HW + px] = (ushort)(w1 & 0xffff);
            v[((size_t)(b * CCH + c + 3)) * HW + px] = (ushort)(w1 >> 16);
        }
    }
}

// ------------------------------------------------------------------
// Kernel B: flash attention, bf16 MFMA 16x16x32, KVBLK = 128.
// Identical to R4 except kT is glds-staged from the PADDED [b][j][KTS]
// global layout (kf b128 reads now 2-way/free instead of 4-way).
// ------------------------------------------------------------------
__global__ __launch_bounds__(256) void attn_kernel(
    const ushort* __restrict__ qT, const ushort* __restrict__ kTg,
    const ushort* __restrict__ vg, const float* __restrict__ x,
    const float* __restrict__ gamma, float* __restrict__ out)
{
    // XCD swizzle: 512 = 8 XCDs x 64; each XCD gets one batch (K/V L2-resident)
    const int blk = ((blockIdx.x & 7) << 6) | (blockIdx.x >> 3);
    const int b   = blk >> 6;
    const int i0  = (blk & 63) << 6;
    const int t   = threadIdx.x;
    const int l   = t & 63;
    const int w   = t >> 6;
    const int lm  = l & 15;   // B-operand lane idx -> D col
    const int lg  = l >> 4;

    __shared__ __align__(16) ushort kT_l[128 * KTS];   // 6KB  [j][KTS] linear
    __shared__ __align__(16) ushort v_l [128 * 128];   // 32KB [c][128j] swizzled granules
    __shared__ __align__(16) ushort P_l [64 * 128];    // 16KB [i][128j] swizzled granules

    // ---- per-lane glds addresses (linear LDS dest; swizzled global src) ----
    // kT tile = 128 rows * KTS = 384 granules: all threads once, waves 0-1 twice
    const ushort* kT_src0 = kTg + ((size_t)b * HW) * KTS + t * 8;
    const ushort* kT_src1 = kTg + ((size_t)b * HW) * KTS + (256 + t) * 8;
    ushort*       kT_dst0 = &kT_l[t * 8];
    ushort*       kT_dst1 = &kT_l[(256 + t) * 8];
    const ushort* v_src[8];
    ushort*       v_dst[8];
#pragma unroll
    for (int it = 0; it < 8; it++) {
        const int idx = t + 256 * it;
        const int c   = idx >> 4;
        const int gs  = (idx & 15) ^ (c & 15);      // involutive granule swizzle
        v_src[it] = vg + ((size_t)(b * CCH + c)) * HW + gs * 8;
        v_dst[it] = &v_l[idx * 8];
    }

    // Q B-frag (log2e pre-folded): lane needs q[i = i0+16w+lm][d = lg*8..]; lg>=2 zero
    bf16x8 qf;
#pragma unroll
    for (int z = 0; z < 8; z++) qf[z] = 0;
    if (lg < 2)
        qf = *(const bf16x8*)(qT + ((size_t)(b * HW + i0 + 16 * w + lm)) * DQK + lg * 8);

    f32x4 zero4;
#pragma unroll
    for (int z = 0; z < 4; z++) zero4[z] = 0.f;

    f32x4 acc[8];
#pragma unroll
    for (int ct = 0; ct < 8; ct++) acc[ct] = zero4;

    float m_i = -1e30f, l_i = 0.f;

    for (int j0 = 0; j0 < HW; j0 += 128) {
        __syncthreads();   // previous tile fully consumed

        // ---- async stage: kT (1-2 glds) + v (8 glds) ----
        glds16(kT_src0 + (size_t)j0 * KTS, kT_dst0);
        if (t < 128)   // waves 0-1 fully active (no partial-wave glds)
            glds16(kT_src1 + (size_t)j0 * KTS, kT_dst1);
#pragma unroll
        for (int it = 0; it < 8; it++)
            glds16(v_src[it] + j0, v_dst[it]);
        __syncthreads();   // emits s_waitcnt vmcnt(0) before s_barrier

        // ---- S^T = mfma(K,Q): s[jt][r] = S[i][j = j0 + jt*16 + lg*4 + r] (exp2 dom) ----
        f32x4 s[8];
#pragma unroll
        for (int jt = 0; jt < 8; jt++) {
            bf16x8 kf = {};
            if (lg < 2)    // exec-masked half-wave read; k>=16 killed by qf zeros
                kf = *(const bf16x8*)&kT_l[(jt * 16 + lm) * KTS + lg * 8];
            s[jt] = __builtin_amdgcn_mfma_f32_16x16x32_bf16(kf, qf, zero4, 0, 0, 0);
        }

        // ---- online softmax, one i per lane ----
        float mx = s[0][0];
#pragma unroll
        for (int jt = 0; jt < 8; jt++)
#pragma unroll
            for (int r = 0; r < 4; r++) mx = fmaxf(mx, s[jt][r]);
        mx = fmaxf(mx, __shfl_xor(mx, 16));
        mx = fmaxf(mx, __shfl_xor(mx, 32));

        float m_new, alpha;
        if (__all(mx - m_i <= 8.f)) {           // T13 defer-rescale
            m_new = m_i; alpha = 1.f;
        } else {
            m_new = fmaxf(m_i, mx);
            alpha = exp2f(m_i - m_new);
#pragma unroll
            for (int ct = 0; ct < 8; ct++) acc[ct] *= alpha;
        }

        float sum = 0.f;
        const int prow = (16 * w + lm) * 128;
#pragma unroll
        for (int jt = 0; jt < 8; jt++) {
            const float p0f = exp2f(s[jt][0] - m_new);
            const float p1f = exp2f(s[jt][1] - m_new);
            const float p2f = exp2f(s[jt][2] - m_new);
            const float p3f = exp2f(s[jt][3] - m_new);
            sum += (p0f + p1f) + (p2f + p3f);
            uint2 pk;
            pk.x = cvt_pk_bf16(p0f, p1f);
            pk.y = cvt_pk_bf16(p2f, p3f);
            const int g = (2 * jt + (lg >> 1)) ^ lm;   // swizzled granule
            *(uint2*)&P_l[prow + g * 8 + (lg & 1) * 4] = pk;
        }
        sum += __shfl_xor(sum, 16);
        sum += __shfl_xor(sum, 32);
        l_i = l_i * alpha + sum;
        m_i = m_new;

        // ---- PV: acc[ct] += v-tile(ct) . P^T (same-wave LDS, lgkmcnt-ordered) ----
        __builtin_amdgcn_s_setprio(1);
#pragma unroll
        for (int ks = 0; ks < 4; ks++) {
            const int g = (4 * ks + lg) ^ lm;          // same swizzle both reads
            const bf16x8 pf = *(const bf16x8*)&P_l[prow + g * 8];
#pragma unroll
            for (int ct = 0; ct < 8; ct++) {
                const bf16x8 vf = *(const bf16x8*)&v_l[(ct * 16 + lm) * 128 + g * 8];
                acc[ct] = __builtin_amdgcn_mfma_f32_16x16x32_bf16(vf, pf, acc[ct], 0, 0, 0);
            }
        }
        __builtin_amdgcn_s_setprio(0);
    }

    // ---- epilogue: out = gamma * (acc / l) + x ----
    const float linv = 1.f / l_i;
    const float gm = gamma[0];
    const int i = 16 * w + lm;
#pragma unroll
    for (int ct = 0; ct < 8; ct++) {
#pragma unroll
        for (int r = 0; r < 4; r++) {
            const int c = ct * 16 + lg * 4 + r;
            const size_t off = ((size_t)(b * CCH + c)) * HW + i0 + i;
            out[off] = gm * (acc[ct][r] * linv) + x[off];
        }
    }
}

extern "C" void kernel_launch(void* const* d_in, const int* in_sizes, int n_in,
                              void* d_out, int out_size, void* d_ws, size_t ws_size,
                              hipStream_t stream)
{
    const float* x     = (const float*)d_in[0];
    const float* Wq    = (const float*)d_in[1];
    const float* bq    = (const float*)d_in[2];
    const float* Wk    = (const float*)d_in[3];
    const float* bk    = (const float*)d_in[4];
    const float* Wv    = (const float*)d_in[5];
    const float* bv    = (const float*)d_in[6];
    const float* gamma = (const float*)d_in[7];
    float* out = (float*)d_out;

    ushort* qT   = (ushort*)d_ws;                        // [8][4096][16]  bf16 (x log2e)
    ushort* kT   = qT + (size_t)BATCH * HW * DQK;        // [8][4096][KTS] bf16 padded
    ushort* v    = kT + (size_t)BATCH * HW * KTS;        // [8][128][4096] bf16
    ushort* Wpad = v  + (size_t)BATCH * CCH * HW;        // [WGRAN*8] bf16 padded

    prep_kernel<<<dim3(43), dim3(256), 0, stream>>>(Wq, Wk, Wv, Wpad);
    qkv_kernel<<<dim3(BATCH * (HW / 64)), dim3(256), 0, stream>>>(
        x, Wpad, bq, bk, bv, qT, kT, v);
    attn_kernel<<<dim3(BATCH * (HW / 64)), dim3(256), 0, stream>>>(
        qT, kT, v, x, gamma, out);
}